// Round 7
// baseline (229.600 us; speedup 1.0000x reference)
//
#include <hip/hip_runtime.h>
#include <cstddef>

// StreamingISTFT fully fused: staged denorm -> FFT32(k2) -> LDS -> FFT32(k1)
// -> window -> LDS frame tile -> overlap-add -> coalesced stores.
// B=8, F=1024(+Nyquist), T=2048, HOP=512, L=2048.
// irfft(2048) = complex IFFT(1024) (real-packing); IFFT(1024) = 32x32 four-step.
//
// R8:  XCD-aware remap: FETCH 446->67 MB.
// R11: staged float4 input: 100->85 us (the staging, NOT the LDS shrink, won).
// R12/R13: more phase-splitting -> 117/115 us. Lesson: VALU issue-work is
//      invariant (~35 us); splitting adds barriers + half-idle phases = stall.
//      R10(33.8KB)~R8(67.6KB) also showed occupancy never improved with LDS.
// R14: recombine winners, delete losers:
//      - FULL X transpose (single write + single read phase, all threads
//        active, 2 barriers) and FULL 8-frame F tile (single phase, no carry
//        registers) -> LDS back to 67.6 KB, barriers ~12 -> 7.
//      - R11's two-superchunk staged float4 input kept verbatim.
//      - transpose twiddle e^{2pi i q r/1024} by incremental complex rotation
//        (2 trans ops/thread instead of 64; 31-step recurrence err ~2e-6).

#define TDIM 2048
#define FDIM 1024
#define TT 8                    // t-columns per block
#define NTOT (512 * 2048)       // output samples per batch
#define SPLANE 4224             // LDS staging plane stride (floats)

static constexpr int kBREV[32] = {0,16,8,24,4,20,12,28,2,18,10,26,6,22,14,30,
                                  1,17,9,25,5,21,13,29,3,19,11,27,7,23,15,31};
// e^{+2*pi*i*r/32}, r=0..15 (inverse-transform sign)
static constexpr float kTR[16] = {
  1.0f, 0.98078528040323044f, 0.92387953251128674f, 0.83146961230254524f,
  0.70710678118654757f, 0.55557023301960218f, 0.38268343236508978f, 0.19509032201612825f,
  0.0f, -0.19509032201612825f, -0.38268343236508978f, -0.55557023301960218f,
  -0.70710678118654757f, -0.83146961230254524f, -0.92387953251128674f, -0.98078528040323044f};
static constexpr float kTI[16] = {
  0.0f, 0.19509032201612825f, 0.38268343236508978f, 0.55557023301960218f,
  0.70710678118654757f, 0.83146961230254524f, 0.92387953251128674f, 0.98078528040323044f,
  1.0f, 0.98078528040323044f, 0.92387953251128674f, 0.83146961230254524f,
  0.70710678118654757f, 0.55557023301960218f, 0.38268343236508978f, 0.19509032201612825f};
// 64th roots of unity: kCC[k2]=cos(2*pi*k2/64), kSS[k2]=sin(2*pi*k2/64)
static constexpr float kCC[32] = {
  1.0f, 0.99518472667219693f, 0.98078528040323044f, 0.95694033573220882f,
  0.92387953251128674f, 0.88192126434835505f, 0.83146961230254524f, 0.77301045336273699f,
  0.70710678118654757f, 0.63439328416364549f, 0.55557023301960218f, 0.47139673682599764f,
  0.38268343236508978f, 0.29028467725446233f, 0.19509032201612825f, 0.098017140329560604f,
  0.0f, -0.098017140329560604f, -0.19509032201612825f, -0.29028467725446233f,
  -0.38268343236508978f, -0.47139673682599764f, -0.55557023301960218f, -0.63439328416364549f,
  -0.70710678118654757f, -0.77301045336273699f, -0.83146961230254524f, -0.88192126434835505f,
  -0.92387953251128674f, -0.95694033573220882f, -0.98078528040323044f, -0.99518472667219693f};
static constexpr float kSS[32] = {
  0.0f, 0.098017140329560604f, 0.19509032201612825f, 0.29028467725446233f,
  0.38268343236508978f, 0.47139673682599764f, 0.55557023301960218f, 0.63439328416364549f,
  0.70710678118654757f, 0.77301045336273699f, 0.83146961230254524f, 0.88192126434835505f,
  0.92387953251128674f, 0.95694033573220882f, 0.98078528040323044f, 0.99518472667219693f,
  1.0f, 0.99518472667219693f, 0.98078528040323044f, 0.95694033573220882f,
  0.92387953251128674f, 0.88192126434835505f, 0.83146961230254524f, 0.77301045336273699f,
  0.70710678118654757f, 0.63439328416364549f, 0.55557023301960218f, 0.47139673682599764f,
  0.38268343236508978f, 0.29028467725446233f, 0.19509032201612825f, 0.098017140329560604f};

template <int H>
__device__ __forceinline__ void fft32_stage(float ar[32], float ai[32]) {
  constexpr int TSTEP = 16 / H;
  #pragma unroll
  for (int g = 0; g < 32; g += 2 * H) {
    #pragma unroll
    for (int j = 0; j < H; ++j) {
      const float twr = kTR[j * TSTEP];
      const float twi = kTI[j * TSTEP];
      const int i0 = g + j, i1 = i0 + H;
      const float tr = twr * ar[i1] - twi * ai[i1];
      const float ti = twr * ai[i1] + twi * ar[i1];
      ar[i1] = ar[i0] - tr; ai[i1] = ai[i0] - ti;
      ar[i0] += tr;         ai[i0] += ti;
    }
  }
}

// In-register radix-2 DIT FFT32 (inverse sign). Input bit-reversed; out natural.
__device__ __forceinline__ void ifft32_core(float ar[32], float ai[32]) {
  fft32_stage<1>(ar, ai);
  fft32_stage<2>(ar, ai);
  fft32_stage<4>(ar, ai);
  fft32_stage<8>(ar, ai);
  fft32_stage<16>(ar, ai);
}

// |v|^(2*PE) * KS via native v_log_f32 + v_exp_f32. v=0 -> 0: ok.
__device__ __forceinline__ float pow_gain(float v, float PE, float KS) {
  return KS * __builtin_amdgcn_exp2f(PE * __builtin_amdgcn_logf(v));
}

__device__ __forceinline__ void denorm4(float4& r, float4& i, float PE, float KS) {
  float g;
  g = pow_gain(r.x * r.x + i.x * i.x, PE, KS); r.x *= g; i.x *= g;
  g = pow_gain(r.y * r.y + i.y * i.y, PE, KS); r.y *= g; i.y *= g;
  g = pow_gain(r.z * r.z + i.z * i.z, PE, KS); r.z *= g; i.z *= g;
  g = pow_gain(r.w * r.w + i.w * i.w, PE, KS); r.w *= g; i.w *= g;
}

// superchunk slot -> global row. SC0: slots [0,256)=rows [0,256), slots
// [256,512)=rows [768,1024), slot 512=row 256. SC1: slot s=row s+256,
// slot 512=row 768.  (Verbatim from R11 -- proven correct.)
template <int SC>
__device__ __forceinline__ int slot_row(int s) {
  return (SC == 0) ? (s < 256 ? s : s + 512) : (s + 256);
}

// Stage-1 pack+bitrev for one superchunk's 16 k2 values, reading denormed S
// from LDS. Mirror-slot identities: slotm(q>0) = (32-q)+32*(15-u);
// slotm(q==0) = 32*(16-u) with SC0 exceptions u=0 -> 0, u=8 -> 512.
template <int SC>
__device__ __forceinline__ void stage1_compute(const float* __restrict__ Sre,
                                               const float* __restrict__ Sim,
                                               int q, int tl, float wc, float ws,
                                               float ar[32], float ai[32]) {
  #pragma unroll
  for (int u = 0; u < 16; ++u) {
    const int k2 = (SC == 0) ? (u < 8 ? u : u + 16) : (u + 8);
    const int slot = q + 32 * u;
    int slotm_zero = 32 * (16 - u);
    if (SC == 0 && u == 0) slotm_zero = 0;
    if (SC == 0 && u == 8) slotm_zero = 512;
    const int slotm_pos = (32 - q) + 32 * (15 - u);
    const int slotm = (q == 0) ? slotm_zero : slotm_pos;

    const float s1r = Sre[slot * 8 + tl],  s1i = Sim[slot * 8 + tl];
    const float s2r = Sre[slotm * 8 + tl], s2i = Sim[slotm * 8 + tl];
    // W[k] = (S1 + conj(S2)) + i*T*(S1 - conj(S2)),  T = e^{i pi k/1024}
    // T = e^{i pi q/1024} * e^{i pi k2/32}  (constant tables, 4 FMA)
    const float cs = wc * kCC[k2] - ws * kSS[k2];
    const float sn = ws * kCC[k2] + wc * kSS[k2];
    const float Pre = s1r + s2r, Pim = s1i - s2i;
    const float Qre = s1r - s2r, Qim = s1i + s2i;
    const float uu = cs * Qim + sn * Qre;
    const float vv = cs * Qre - sn * Qim;
    float wr = Pre - uu, wi = Pim + vv;
    if (q == 0 && k2 == 0) { wr = s1r; wi = s1r; }  // DC: Im dropped, Nyquist=0
    ar[kBREV[k2]] = wr; ai[kBREV[k2]] = wi;
  }
}

// Full-X layout: X(t, k1, r) = k1*264 + r*8 + t (264 = 32*8 + 8 pad).
// Stage-1 write lanes (t,k1): bank = (8k1+t+8r) -> 2-way. Stage-2 read
// lanes (t,r): bank = (8r+t+8k1) -> 2-way. Max index 8439 < 8448.
#define XIDX(t, k1, r) ((k1) * 264 + (r) * 8 + (t))
#define FSTR 2054               // frame tile row stride (even: float2 writes)

__global__ __launch_bounds__(256) void istft_fused(const float* __restrict__ in,
                                                   const float* __restrict__ invw,
                                                   float* __restrict__ out) {
  __shared__ float buf[16896];          // 67.6 KB, three overlapped tenants:
  float* Sre = buf;                     //  staging: [0,4104) + [4224,8328)
  float* Sim = buf + SPLANE;
  float* Xr  = buf;                     //  X full: [0,8448) + [8448,16896)
  float* Xi  = buf + 8448;
  float* Fh  = buf;                     //  frames: [0,16425)

  const int tid = threadIdx.x;
  const int tl  = tid & 7;              // t within tile
  const int q   = tid >> 3;             // k1 (stage 1) / r (stage 2)

  // XCD-aware remap (R8): each XCD owns 32 contiguous t-tiles of one batch.
  const int id   = blockIdx.x;          // 0..2047
  const int xcd  = id & 7;
  const int slot = id >> 3;             // 0..255
  const int b    = slot >> 5;           // 0..7
  const int tile = xcd * 32 + (slot & 31);  // 0..255
  const int t0   = tile * TT;

  const float* re_p = in + ((size_t)b * 2 + 0) * ((size_t)FDIM * TDIM);
  const float* im_p = in + ((size_t)b * 2 + 1) * ((size_t)FDIM * TDIM);

  const float KS = (float)(exp((-1.0 / 0.65) * log(0.06)) / 2048.0);
  const float PE = 7.0f / 26.0f;

  // pack twiddle base: e^{i*pi*q/1024}
  const float aq = 3.0679615757712824e-3f * (float)q;
  const float wc = __cosf(aq), ws = __sinf(aq);

  float ar[32], ai[32];

  // ---- Stage 1a: load + denorm superchunk A; stage to LDS (R11 verbatim) ----
  {
    float4 reA[4], imA[4];
    #pragma unroll
    for (int j = 0; j < 4; ++j) {
      const int f = tid + 256 * j;
      const int s = f >> 1, cg = f & 1;
      const int row = slot_row<0>(s);
      reA[j] = *(const float4*)(re_p + (size_t)row * TDIM + t0 + 4 * cg);
      imA[j] = *(const float4*)(im_p + (size_t)row * TDIM + t0 + 4 * cg);
    }
    float4 exRe, exIm;                  // extra row 256 -> slot 512 (tid<2)
    if (tid < 2) {
      exRe = *(const float4*)(re_p + (size_t)256 * TDIM + t0 + 4 * tid);
      exIm = *(const float4*)(im_p + (size_t)256 * TDIM + t0 + 4 * tid);
    }
    #pragma unroll
    for (int j = 0; j < 4; ++j) {
      const int f = tid + 256 * j;
      const int s = f >> 1, cg = f & 1;
      denorm4(reA[j], imA[j], PE, KS);
      *(float4*)(Sre + s * 8 + 4 * cg) = reA[j];
      *(float4*)(Sim + s * 8 + 4 * cg) = imA[j];
    }
    if (tid < 2) {
      denorm4(exRe, exIm, PE, KS);
      *(float4*)(Sre + 512 * 8 + 4 * tid) = exRe;
      *(float4*)(Sim + 512 * 8 + 4 * tid) = exIm;
    }

    // ---- issue superchunk B global loads now (consumed after compute A) ----
    float4 reB[4], imB[4];
    #pragma unroll
    for (int j = 0; j < 4; ++j) {
      const int f = tid + 256 * j;
      const int s = f >> 1, cg = f & 1;
      const int row = slot_row<1>(s);
      reB[j] = *(const float4*)(re_p + (size_t)row * TDIM + t0 + 4 * cg);
      imB[j] = *(const float4*)(im_p + (size_t)row * TDIM + t0 + 4 * cg);
    }
    float4 exReB, exImB;                // extra row 768 -> slot 512 (tid<2)
    if (tid < 2) {
      exReB = *(const float4*)(re_p + (size_t)768 * TDIM + t0 + 4 * tid);
      exImB = *(const float4*)(im_p + (size_t)768 * TDIM + t0 + 4 * tid);
    }
    __syncthreads();

    // ---- Stage 1b: compute superchunk A (k2 in [0,8) u [24,32)) ----
    stage1_compute<0>(Sre, Sim, q, tl, wc, ws, ar, ai);
    __syncthreads();                    // all A reads done before B overwrites

    // ---- Stage 1c: stage superchunk B; compute (k2 in [8,24)) ----
    #pragma unroll
    for (int j = 0; j < 4; ++j) {
      const int f = tid + 256 * j;
      const int s = f >> 1, cg = f & 1;
      denorm4(reB[j], imB[j], PE, KS);
      *(float4*)(Sre + s * 8 + 4 * cg) = reB[j];
      *(float4*)(Sim + s * 8 + 4 * cg) = imB[j];
    }
    if (tid < 2) {
      denorm4(exReB, exImB, PE, KS);
      *(float4*)(Sre + 512 * 8 + 4 * tid) = exReB;
      *(float4*)(Sim + 512 * 8 + 4 * tid) = exImB;
    }
    __syncthreads();
    stage1_compute<1>(Sre, Sim, q, tl, wc, ws, ar, ai);
    __syncthreads();                    // staging dead; X may overwrite buf
  }

  // ---- FFT32 over k2 ----
  ifft32_core(ar, ai);

  // ---- Transpose through FULL X: one write phase, one read phase ----
  // Inter-stage twiddle e^{2 pi i q r/1024} by incremental rotation:
  // w(0)=1, w(r+1)=w(r)*delta, delta=e^{2 pi i q/1024}. 31-step recurrence
  // error ~2e-6 relative -- negligible vs 0.0625 absmax.
  {
    const float aq2 = 6.1359231515425649e-3f * (float)q;
    const float dc = __cosf(aq2), dsn = __sinf(aq2);
    float cs = 1.0f, sn = 0.0f;
    #pragma unroll
    for (int r = 0; r < 32; ++r) {
      Xr[XIDX(tl, q, r)] = cs * ar[r] - sn * ai[r];
      Xi[XIDX(tl, q, r)] = cs * ai[r] + sn * ar[r];
      const float ncs = cs * dc - sn * dsn;
      sn = cs * dsn + sn * dc;
      cs = ncs;
    }
  }
  __syncthreads();
  float zr[32], zi[32];
  #pragma unroll
  for (int i = 0; i < 32; ++i) {        // bit-reversed k1 load order
    zr[i] = Xr[XIDX(tl, kBREV[i], q)];
    zi[i] = Xi[XIDX(tl, kBREV[i], q)];
  }
  __syncthreads();                      // X dead; F tile may overwrite buf

  // ---- Stage 2: FFT32 over k1 ----
  ifft32_core(zr, zi);

  // ---- Full 8-frame tile (all threads active) + single-pass OLA ----
  // frames[tl][l], l = 2*(q+32s)+{0,1}; thread writes its own frame row.
  #pragma unroll
  for (int s = 0; s < 32; ++s) {
    const int l0 = 2 * q + 64 * s;
    const float2 w2 = *(const float2*)(invw + l0);
    float2 fv; fv.x = zr[s] * w2.x; fv.y = zi[s] * w2.y;
    *(float2*)(Fh + tl * FSTR + l0) = fv;
  }
  __syncthreads();

  // ---- OLA: out[512*t' + j] = sum_c F[t'-c-t0][j + 512c] ----
  float* ob = out + (size_t)b * NTOT;
  for (int rel = 0; rel < 11; ++rel) {
    const int tp = t0 + rel;
    if (tp > 2047) break;
    #pragma unroll
    for (int half = 0; half < 2; ++half) {
      const int j = tid + 256 * half;   // lanes j-consecutive -> coalesced
      float v = 0.0f;
      #pragma unroll
      for (int c = 0; c < 4; ++c) {
        const int tt = rel - c;
        if (tt >= 0 && tt < TT) v += Fh[tt * FSTR + j + 512 * c];
      }
      const int n = tp * 512 + j;
      if (rel >= 3 && rel <= 7) ob[n] = v;          // all 4 contributors in-block
      else atomicAdd(&ob[n], v);                     // tile boundary: 2 writers
    }
  }
}

extern "C" void kernel_launch(void* const* d_in, const int* in_sizes, int n_in,
                              void* d_out, int out_size, void* d_ws, size_t ws_size,
                              hipStream_t stream) {
  (void)in_sizes; (void)n_in; (void)d_ws; (void)ws_size;
  const float* in   = (const float*)d_in[0];
  const float* invw = (const float*)d_in[1];
  float* out = (float*)d_out;
  hipMemsetAsync(out, 0, (size_t)out_size * sizeof(float), stream);
  istft_fused<<<dim3(TDIM / TT * 8), 256, 0, stream>>>(in, invw, out);
}

// Round 8
// 229.087 us; speedup vs baseline: 1.0022x; 1.0022x over previous
//
#include <hip/hip_runtime.h>
#include <cstddef>

// StreamingISTFT fully fused: staged denorm -> FFT32(k2) -> LDS -> FFT32(k1)
// -> window -> LDS frame tile -> overlap-add -> coalesced stores.
// B=8, F=1024(+Nyquist), T=2048, HOP=512, L=2048.
// irfft(2048) = complex IFFT(1024) (real-packing); IFFT(1024) = 32x32 four-step.
//
// R8:  XCD-aware remap: FETCH 446->67 MB.
// R11: staged float4 input: 100->85 us.
// R12/R13: phase-splitting -> 115-117 us REGRESSIONS (stall moved, not work).
// R14: recombined simple structure + twiddle recurrence: 85 us. Invariant:
//      dur ~85 us across occupancy 19-30% and 7-24 barriers -> per-wave
//      VALU (~30 us) and LDS-pipe (~29 us) work serialize; cut the work.
// R15: complex-INTERLEAVED LDS (float2) everywhere:
//      - staging Sri[slot][t][re,im]: pack reads 128 b32 -> 64 b64
//      - X transpose interleaved: 128 b32 -> 64 b64
//      - OLA: 64 b32 reads -> 32 b64; interior stores as float2
//      LDS instrs ~352 -> ~192/thread; halves addr-VALU + lgkmcnt points.
//      All read patterns uniform 4-lanes-per-bank-pair (b64 floor).
//      NOTE: SQ_LDS_BANK_CONFLICT counter may rise (b64 pair aliasing) --
//      cycles go DOWN; judge by dur_us.

#define TDIM 2048
#define FDIM 1024
#define TT 8                    // t-columns per block
#define NTOT (512 * 2048)       // output samples per batch

static constexpr int kBREV[32] = {0,16,8,24,4,20,12,28,2,18,10,26,6,22,14,30,
                                  1,17,9,25,5,21,13,29,3,19,11,27,7,23,15,31};
// e^{+2*pi*i*r/32}, r=0..15 (inverse-transform sign)
static constexpr float kTR[16] = {
  1.0f, 0.98078528040323044f, 0.92387953251128674f, 0.83146961230254524f,
  0.70710678118654757f, 0.55557023301960218f, 0.38268343236508978f, 0.19509032201612825f,
  0.0f, -0.19509032201612825f, -0.38268343236508978f, -0.55557023301960218f,
  -0.70710678118654757f, -0.83146961230254524f, -0.92387953251128674f, -0.98078528040323044f};
static constexpr float kTI[16] = {
  0.0f, 0.19509032201612825f, 0.38268343236508978f, 0.55557023301960218f,
  0.70710678118654757f, 0.83146961230254524f, 0.92387953251128674f, 0.98078528040323044f,
  1.0f, 0.98078528040323044f, 0.92387953251128674f, 0.83146961230254524f,
  0.70710678118654757f, 0.55557023301960218f, 0.38268343236508978f, 0.19509032201612825f};
// 64th roots of unity: kCC[k2]=cos(2*pi*k2/64), kSS[k2]=sin(2*pi*k2/64)
static constexpr float kCC[32] = {
  1.0f, 0.99518472667219693f, 0.98078528040323044f, 0.95694033573220882f,
  0.92387953251128674f, 0.88192126434835505f, 0.83146961230254524f, 0.77301045336273699f,
  0.70710678118654757f, 0.63439328416364549f, 0.55557023301960218f, 0.47139673682599764f,
  0.38268343236508978f, 0.29028467725446233f, 0.19509032201612825f, 0.098017140329560604f,
  0.0f, -0.098017140329560604f, -0.19509032201612825f, -0.29028467725446233f,
  -0.38268343236508978f, -0.47139673682599764f, -0.55557023301960218f, -0.63439328416364549f,
  -0.70710678118654757f, -0.77301045336273699f, -0.83146961230254524f, -0.88192126434835505f,
  -0.92387953251128674f, -0.95694033573220882f, -0.98078528040323044f, -0.99518472667219693f};
static constexpr float kSS[32] = {
  0.0f, 0.098017140329560604f, 0.19509032201612825f, 0.29028467725446233f,
  0.38268343236508978f, 0.47139673682599764f, 0.55557023301960218f, 0.63439328416364549f,
  0.70710678118654757f, 0.77301045336273699f, 0.83146961230254524f, 0.88192126434835505f,
  0.92387953251128674f, 0.95694033573220882f, 0.98078528040323044f, 0.99518472667219693f,
  1.0f, 0.99518472667219693f, 0.98078528040323044f, 0.95694033573220882f,
  0.92387953251128674f, 0.88192126434835505f, 0.83146961230254524f, 0.77301045336273699f,
  0.70710678118654757f, 0.63439328416364549f, 0.55557023301960218f, 0.47139673682599764f,
  0.38268343236508978f, 0.29028467725446233f, 0.19509032201612825f, 0.098017140329560604f};

template <int H>
__device__ __forceinline__ void fft32_stage(float ar[32], float ai[32]) {
  constexpr int TSTEP = 16 / H;
  #pragma unroll
  for (int g = 0; g < 32; g += 2 * H) {
    #pragma unroll
    for (int j = 0; j < H; ++j) {
      const float twr = kTR[j * TSTEP];
      const float twi = kTI[j * TSTEP];
      const int i0 = g + j, i1 = i0 + H;
      const float tr = twr * ar[i1] - twi * ai[i1];
      const float ti = twr * ai[i1] + twi * ar[i1];
      ar[i1] = ar[i0] - tr; ai[i1] = ai[i0] - ti;
      ar[i0] += tr;         ai[i0] += ti;
    }
  }
}

// In-register radix-2 DIT FFT32 (inverse sign). Input bit-reversed; out natural.
__device__ __forceinline__ void ifft32_core(float ar[32], float ai[32]) {
  fft32_stage<1>(ar, ai);
  fft32_stage<2>(ar, ai);
  fft32_stage<4>(ar, ai);
  fft32_stage<8>(ar, ai);
  fft32_stage<16>(ar, ai);
}

// |v|^(2*PE) * KS via native v_log_f32 + v_exp_f32. v=0 -> 0: ok.
__device__ __forceinline__ float pow_gain(float v, float PE, float KS) {
  return KS * __builtin_amdgcn_exp2f(PE * __builtin_amdgcn_logf(v));
}

__device__ __forceinline__ void denorm4(float4& r, float4& i, float PE, float KS) {
  float g;
  g = pow_gain(r.x * r.x + i.x * i.x, PE, KS); r.x *= g; i.x *= g;
  g = pow_gain(r.y * r.y + i.y * i.y, PE, KS); r.y *= g; i.y *= g;
  g = pow_gain(r.z * r.z + i.z * i.z, PE, KS); r.z *= g; i.z *= g;
  g = pow_gain(r.w * r.w + i.w * i.w, PE, KS); r.w *= g; i.w *= g;
}

// superchunk slot -> global row. SC0: slots [0,256)=rows [0,256), slots
// [256,512)=rows [768,1024), slot 512=row 256. SC1: slot s=row s+256,
// slot 512=row 768.  (Proven in R11/R14.)
template <int SC>
__device__ __forceinline__ int slot_row(int s) {
  return (SC == 0) ? (s < 256 ? s : s + 512) : (s + 256);
}

// Interleaved staging: Sri[slot*16 + t*2] = re, +1 = im. 513 slots.
// Stage-1 pack+bitrev for one superchunk's 16 k2 values. Mirror-slot
// identities (proven R11/R14): slotm(q>0) = (32-q)+32*(15-u);
// slotm(q==0) = 32*(16-u) with SC0 exceptions u=0 -> 0, u=8 -> 512.
template <int SC>
__device__ __forceinline__ void stage1_compute(const float* __restrict__ Sri,
                                               int q, int tl, float wc, float ws,
                                               float ar[32], float ai[32]) {
  #pragma unroll
  for (int u = 0; u < 16; ++u) {
    const int k2 = (SC == 0) ? (u < 8 ? u : u + 16) : (u + 8);
    const int slot = q + 32 * u;
    int slotm_zero = 32 * (16 - u);
    if (SC == 0 && u == 0) slotm_zero = 0;
    if (SC == 0 && u == 8) slotm_zero = 512;
    const int slotm_pos = (32 - q) + 32 * (15 - u);
    const int slotm = (q == 0) ? slotm_zero : slotm_pos;

    const float2 s1 = *(const float2*)(Sri + slot * 16 + 2 * tl);
    const float2 s2 = *(const float2*)(Sri + slotm * 16 + 2 * tl);
    // W[k] = (S1 + conj(S2)) + i*T*(S1 - conj(S2)),  T = e^{i pi k/1024}
    // T = e^{i pi q/1024} * e^{i pi k2/32}  (constant tables, 4 FMA)
    const float cs = wc * kCC[k2] - ws * kSS[k2];
    const float sn = ws * kCC[k2] + wc * kSS[k2];
    const float Pre = s1.x + s2.x, Pim = s1.y - s2.y;
    const float Qre = s1.x - s2.x, Qim = s1.y + s2.y;
    const float uu = cs * Qim + sn * Qre;
    const float vv = cs * Qre - sn * Qim;
    float wr = Pre - uu, wi = Pim + vv;
    if (q == 0 && k2 == 0) { wr = s1.x; wi = s1.x; }  // DC: Im dropped, Nyquist=0
    ar[kBREV[k2]] = wr; ai[kBREV[k2]] = wi;
  }
}

// Interleaved full-X: float2 index XC = k1*264 + r*8 + t (264 = 33*8 pad).
// Float addr = 2*XC; max 2*8439+1 = 16879 < 16896. Writes/reads uniform
// 4-lanes-per-bank-pair (the b64 floor).
#define XC(t, k1, r) ((k1) * 264 + (r) * 8 + (t))
#define FSTR 2054               // frame tile row stride (even: float2 ops)

__global__ __launch_bounds__(256) void istft_fused(const float* __restrict__ in,
                                                   const float* __restrict__ invw,
                                                   float* __restrict__ out) {
  __shared__ float buf[16896];          // 67.6 KB, three overlapped tenants:
  float* Sri = buf;                     //  staging (interleaved): [0,8208)
  float* Xc  = buf;                     //  X (interleaved): [0,16880)
  float* Fh  = buf;                     //  frames: [0,16426)

  const int tid = threadIdx.x;
  const int tl  = tid & 7;              // t within tile
  const int q   = tid >> 3;             // k1 (stage 1) / r (stage 2)

  // XCD-aware remap (R8): each XCD owns 32 contiguous t-tiles of one batch.
  const int id   = blockIdx.x;          // 0..2047
  const int xcd  = id & 7;
  const int slot = id >> 3;             // 0..255
  const int b    = slot >> 5;           // 0..7
  const int tile = xcd * 32 + (slot & 31);  // 0..255
  const int t0   = tile * TT;

  const float* re_p = in + ((size_t)b * 2 + 0) * ((size_t)FDIM * TDIM);
  const float* im_p = in + ((size_t)b * 2 + 1) * ((size_t)FDIM * TDIM);

  const float KS = (float)(exp((-1.0 / 0.65) * log(0.06)) / 2048.0);
  const float PE = 7.0f / 26.0f;

  // pack twiddle base: e^{i*pi*q/1024}
  const float aq = 3.0679615757712824e-3f * (float)q;
  const float wc = __cosf(aq), ws = __sinf(aq);

  float ar[32], ai[32];

  // ---- Stage 1: superchunk A load/denorm/stage; B loads in flight ----
  {
    float4 reA[4], imA[4];
    #pragma unroll
    for (int j = 0; j < 4; ++j) {
      const int f = tid + 256 * j;
      const int s = f >> 1, cg = f & 1;
      const int row = slot_row<0>(s);
      reA[j] = *(const float4*)(re_p + (size_t)row * TDIM + t0 + 4 * cg);
      imA[j] = *(const float4*)(im_p + (size_t)row * TDIM + t0 + 4 * cg);
    }
    float4 exRe, exIm;                  // extra row 256 -> slot 512 (tid<2)
    if (tid < 2) {
      exRe = *(const float4*)(re_p + (size_t)256 * TDIM + t0 + 4 * tid);
      exIm = *(const float4*)(im_p + (size_t)256 * TDIM + t0 + 4 * tid);
    }
    #pragma unroll
    for (int j = 0; j < 4; ++j) {
      const int f = tid + 256 * j;
      const int s = f >> 1, cg = f & 1;
      denorm4(reA[j], imA[j], PE, KS);
      const float4 w0 = {reA[j].x, imA[j].x, reA[j].y, imA[j].y};
      const float4 w1 = {reA[j].z, imA[j].z, reA[j].w, imA[j].w};
      *(float4*)(Sri + s * 16 + 8 * cg)     = w0;
      *(float4*)(Sri + s * 16 + 8 * cg + 4) = w1;
    }
    if (tid < 2) {
      denorm4(exRe, exIm, PE, KS);
      const float4 w0 = {exRe.x, exIm.x, exRe.y, exIm.y};
      const float4 w1 = {exRe.z, exIm.z, exRe.w, exIm.w};
      *(float4*)(Sri + 512 * 16 + 8 * tid)     = w0;
      *(float4*)(Sri + 512 * 16 + 8 * tid + 4) = w1;
    }

    // issue superchunk B global loads now (consumed after compute A)
    float4 reB[4], imB[4];
    #pragma unroll
    for (int j = 0; j < 4; ++j) {
      const int f = tid + 256 * j;
      const int s = f >> 1, cg = f & 1;
      const int row = slot_row<1>(s);
      reB[j] = *(const float4*)(re_p + (size_t)row * TDIM + t0 + 4 * cg);
      imB[j] = *(const float4*)(im_p + (size_t)row * TDIM + t0 + 4 * cg);
    }
    float4 exReB, exImB;                // extra row 768 -> slot 512 (tid<2)
    if (tid < 2) {
      exReB = *(const float4*)(re_p + (size_t)768 * TDIM + t0 + 4 * tid);
      exImB = *(const float4*)(im_p + (size_t)768 * TDIM + t0 + 4 * tid);
    }
    __syncthreads();

    // compute superchunk A (k2 in [0,8) u [24,32))
    stage1_compute<0>(Sri, q, tl, wc, ws, ar, ai);
    __syncthreads();                    // all A reads done before B overwrites

    // stage superchunk B; compute (k2 in [8,24))
    #pragma unroll
    for (int j = 0; j < 4; ++j) {
      const int f = tid + 256 * j;
      const int s = f >> 1, cg = f & 1;
      denorm4(reB[j], imB[j], PE, KS);
      const float4 w0 = {reB[j].x, imB[j].x, reB[j].y, imB[j].y};
      const float4 w1 = {reB[j].z, imB[j].z, reB[j].w, imB[j].w};
      *(float4*)(Sri + s * 16 + 8 * cg)     = w0;
      *(float4*)(Sri + s * 16 + 8 * cg + 4) = w1;
    }
    if (tid < 2) {
      denorm4(exReB, exImB, PE, KS);
      const float4 w0 = {exReB.x, exImB.x, exReB.y, exImB.y};
      const float4 w1 = {exReB.z, exImB.z, exReB.w, exImB.w};
      *(float4*)(Sri + 512 * 16 + 8 * tid)     = w0;
      *(float4*)(Sri + 512 * 16 + 8 * tid + 4) = w1;
    }
    __syncthreads();
    stage1_compute<1>(Sri, q, tl, wc, ws, ar, ai);
    __syncthreads();                    // staging dead; X may overwrite buf
  }

  // ---- FFT32 over k2 ----
  ifft32_core(ar, ai);

  // ---- Transpose through FULL interleaved X ----
  // Inter-stage twiddle e^{2 pi i q r/1024} by incremental rotation
  // (31-step recurrence err ~2e-6, negligible vs 0.0625 absmax).
  {
    const float aq2 = 6.1359231515425649e-3f * (float)q;
    const float dc = __cosf(aq2), dsn = __sinf(aq2);
    float cs = 1.0f, sn = 0.0f;
    #pragma unroll
    for (int r = 0; r < 32; ++r) {
      const float2 xv = {cs * ar[r] - sn * ai[r], cs * ai[r] + sn * ar[r]};
      *(float2*)(Xc + 2 * XC(tl, q, r)) = xv;
      const float ncs = cs * dc - sn * dsn;
      sn = cs * dsn + sn * dc;
      cs = ncs;
    }
  }
  __syncthreads();
  float zr[32], zi[32];
  #pragma unroll
  for (int i = 0; i < 32; ++i) {        // bit-reversed k1 load order
    const float2 zv = *(const float2*)(Xc + 2 * XC(tl, kBREV[i], q));
    zr[i] = zv.x; zi[i] = zv.y;
  }
  __syncthreads();                      // X dead; F tile may overwrite buf

  // ---- Stage 2: FFT32 over k1 ----
  ifft32_core(zr, zi);

  // ---- Full 8-frame tile (all threads active) + single-pass OLA ----
  // frames[tl][l], l = 2*(q+32s)+{0,1}; thread writes its own frame row.
  #pragma unroll
  for (int s = 0; s < 32; ++s) {
    const int l0 = 2 * q + 64 * s;
    const float2 w2 = *(const float2*)(invw + l0);
    const float2 fv = {zr[s] * w2.x, zi[s] * w2.y};
    *(float2*)(Fh + tl * FSTR + l0) = fv;
  }
  __syncthreads();

  // ---- OLA (float2 per thread): out[512*t' + j] = sum_c F[t'-c-t0][j+512c] ----
  float* ob = out + (size_t)b * NTOT;
  const int j2 = 2 * tid;               // thread owns samples j2, j2+1
  for (int rel = 0; rel < 11; ++rel) {
    const int tp = t0 + rel;
    if (tp > 2047) break;
    float2 v = {0.0f, 0.0f};
    #pragma unroll
    for (int c = 0; c < 4; ++c) {
      const int tt = rel - c;
      if (tt >= 0 && tt < TT) {
        const float2 f = *(const float2*)(Fh + tt * FSTR + j2 + 512 * c);
        v.x += f.x; v.y += f.y;
      }
    }
    const int n = tp * 512 + j2;
    if (rel >= 3 && rel <= 7) {
      *(float2*)(ob + n) = v;           // all 4 contributors in-block
    } else {
      atomicAdd(&ob[n], v.x);           // tile boundary: 2 writers
      atomicAdd(&ob[n + 1], v.y);
    }
  }
}

extern "C" void kernel_launch(void* const* d_in, const int* in_sizes, int n_in,
                              void* d_out, int out_size, void* d_ws, size_t ws_size,
                              hipStream_t stream) {
  (void)in_sizes; (void)n_in; (void)d_ws; (void)ws_size;
  const float* in   = (const float*)d_in[0];
  const float* invw = (const float*)d_in[1];
  float* out = (float*)d_out;
  hipMemsetAsync(out, 0, (size_t)out_size * sizeof(float), stream);
  istft_fused<<<dim3(TDIM / TT * 8), 256, 0, stream>>>(in, invw, out);
}